// Round 23
// baseline (71.710 us; speedup 1.0000x reference)
//
#include <hip/hip_runtime.h>
#include <math.h>

#define B_    32
#define NV    32768
#define LA    64
#define DIM   128
#define OUTD  7
#define TOPK  10
#define CHUNK 1024
#define NCH   (NV / CHUNK)   // 32
#define NMW   (NV / 32)      // 1024 mask words per batch
#define MAXU  (LA * TOPK)    // 640
#define NSEG  16             // gather segments per batch
#define LCAP  24             // LDS candidate slots per (block, ligand)

typedef unsigned long long u64;

// ---------------- K1: per-(b,l) sample threshold, ONE wave/task -----------------
// grid (LA, B_), block 64. Prefetch-then-insert. Zeros cnt + maskG; writes the
// packed per-ligand filter constants (Ax,Ay,Az,TH) + Cl for k2's scalar loads.
__global__ void k1_threshold(const float* __restrict__ pos,
                             const float* __restrict__ lig,
                             unsigned int* __restrict__ cnt,
                             unsigned int* __restrict__ maskG,
                             float4* __restrict__ ligC,
                             float* __restrict__ ligCl) {
  const int l = blockIdx.x, b = blockIdx.y;
  const int lane = threadIdx.x;
  const int bl = b * LA + l;
  if (lane == 0) cnt[bl] = 0u;
  if (lane >= 32 && lane < 48) maskG[b * NMW + l * 16 + (lane - 32)] = 0u;
  const float lx = lig[bl * 3 + 0];
  const float ly = lig[bl * 3 + 1];
  const float lz = lig[bl * 3 + 2];
  const float* pb = pos + (size_t)b * NV * 3;
  float d2a[16];
#pragma unroll
  for (int k = 0; k < 16; ++k) {
    int v = lane + 64 * k;
    float dx = pb[v * 3 + 0] - lx;
    float dy = pb[v * 3 + 1] - ly;
    float dz = pb[v * 3 + 2] - lz;
    d2a[k] = fmaf(dx, dx, fmaf(dy, dy, dz * dz));
  }
  float s[TOPK];
#pragma unroll
  for (int i = 0; i < TOPK; ++i) s[i] = INFINITY;
#pragma unroll
  for (int k = 0; k < 16; ++k) {
    float d2 = d2a[k];
    if (d2 < s[TOPK - 1]) {
      s[TOPK - 1] = d2;
#pragma unroll
      for (int i = TOPK - 1; i >= 1; --i)
        if (s[i] < s[i - 1]) { float t = s[i]; s[i] = s[i - 1]; s[i - 1] = t; }
    }
  }
  float T10 = 0.f;
  for (int r = 0; r < TOPK; ++r) {
    float v = s[0];
#pragma unroll
    for (int o = 1; o < 64; o <<= 1) v = fminf(v, __shfl_xor(v, o, 64));
    T10 = v;
    if (s[0] == v) {  // dup-consume only enlarges T: safe
#pragma unroll
      for (int i = 0; i < TOPK - 1; ++i) s[i] = s[i + 1];
      s[TOPK - 1] = INFINITY;
    }
  }
  if (lane == 0) {
    float Cl = lx * lx + ly * ly + lz * lz;
    ligC[bl] = make_float4(-2.f * lx, -2.f * ly, -2.f * lz, T10 + 0.01f - Cl);
    ligCl[bl] = Cl;
  }
}

// ---------------- K2: filter, verts-in-VGPRs / ligand-consts-in-SGPRs -----------
// grid (NCH, B_) = 1024 blocks, block 256. 4 verts per thread from global
// (coalesced, pp precomputed); ligand constants via wave-uniform loads (scalar
// path). LDS used ONLY for candidate buffers -> zero per-eval LDS reads.
__global__ void k2_filter(const float* __restrict__ pos,
                          const float4* __restrict__ ligC,
                          const float* __restrict__ ligCl,
                          unsigned int* __restrict__ cnt,
                          u64* __restrict__ cand, int cap) {
  __shared__ u64 lcand[LA][LCAP];       // 12 KB
  __shared__ unsigned lcnt[LA];         // 256 B
  __shared__ unsigned gbaseS[LA];       // 256 B
  const int c = blockIdx.x, b = blockIdx.y;
  const int tid = threadIdx.x;
  const int base = c * CHUNK;
  if (tid < LA) lcnt[tid] = 0u;
  __syncthreads();
  const float* pb = pos + ((size_t)b * NV + base) * 3;
  float4 P[4];
#pragma unroll
  for (int k = 0; k < 4; ++k) {
    int v = tid + 256 * k;
    float px = pb[v * 3 + 0];
    float py = pb[v * 3 + 1];
    float pz = pb[v * 3 + 2];
    P[k] = make_float4(px, py, pz, fmaf(px, px, fmaf(py, py, pz * pz)));
  }
  const float4* lc = ligC + b * LA;    // wave-uniform loop index -> s_load
  const float* lcl = ligCl + b * LA;
  for (int l = 0; l < LA; ++l) {
    float4 A = lc[l];                  // Ax,Ay,Az,TH
#pragma unroll
    for (int k = 0; k < 4; ++k) {
      float t = fmaf(P[k].x, A.x, fmaf(P[k].y, A.y, fmaf(P[k].z, A.z, P[k].w)));
      if (t <= A.w) {
        float d2 = fmaxf(t + lcl[l], 0.f);   // clamp keeps bit-order monotone
        int v = base + tid + 256 * k;
        u64 key = ((u64)__float_as_uint(d2) << 32) | (unsigned)v;
        unsigned p2 = atomicAdd(&lcnt[l], 1u);
        if (p2 < (unsigned)LCAP) lcand[l][p2] = key;
        else {  // rare overflow: direct global append (set still complete)
          unsigned pidx = atomicAdd(&cnt[b * LA + l], 1u);
          if (pidx < (unsigned)cap) cand[(size_t)(b * LA + l) * cap + pidx] = key;
        }
      }
    }
  }
  __syncthreads();
  if (tid < LA) {
    int mcount = (int)min(lcnt[tid], (unsigned)LCAP);
    gbaseS[tid] = (mcount > 0) ? atomicAdd(&cnt[b * LA + tid], (unsigned)mcount) : 0u;
  }
  __syncthreads();
  for (int idx = tid; idx < LA * LCAP; idx += 256) {
    const int ll = idx / LCAP, i = idx - ll * LCAP;
    if (i < (int)min(lcnt[ll], (unsigned)LCAP)) {
      unsigned g = gbaseS[ll] + (unsigned)i;
      if (g < (unsigned)cap) cand[(size_t)(b * LA + ll) * cap + g] = lcand[ll][i];
    }
  }
}

// ---------------- K3: exact top-10 merge over precomputed keys, 1 wave/task -----
// grid 2048, block 64.
__global__ void k3_select(const unsigned int* __restrict__ cnt,
                          const u64* __restrict__ cand, int cap,
                          unsigned int* __restrict__ maskG) {
  const int bl = blockIdx.x;
  const int b = bl / LA;
  const int lane = threadIdx.x;
  int n = (int)min(cnt[bl], (unsigned)cap);
  u64 s[TOPK];
#pragma unroll
  for (int i = 0; i < TOPK; ++i) s[i] = 0xFFFFFFFFFFFFFFFFull;
  for (int i = lane; i < n; i += 64) {
    u64 key = cand[(size_t)bl * cap + i];
    if (key < s[TOPK - 1]) {
      s[TOPK - 1] = key;
#pragma unroll
      for (int i2 = TOPK - 1; i2 >= 1; --i2)
        if (s[i2] < s[i2 - 1]) { u64 t = s[i2]; s[i2] = s[i2 - 1]; s[i2 - 1] = t; }
    }
  }
  int prev = 0, myidx = 0;
  for (int r = 0; r < TOPK; ++r) {
    u64 v = s[0];
#pragma unroll
    for (int o = 1; o < 64; o <<= 1) {
      u64 other = __shfl_xor(v, o, 64);
      v = (other < v) ? other : v;
    }
    if (s[0] == v) {  // keys unique: exact consume
#pragma unroll
      for (int i = 0; i < TOPK - 1; ++i) s[i] = s[i + 1];
      s[TOPK - 1] = 0xFFFFFFFFFFFFFFFFull;
    }
    int idx = (int)(unsigned)(v & 0xFFFFFFFFu);
    if ((v >> 32) == 0xFFFFFFFFull) idx = prev;  // pad guard (n>=10 always)
    prev = idx;
    if (lane == r) myidx = idx;
  }
  if (lane < TOPK)
    atomicOr(&maskG[b * NMW + (myidx >> 5)], 1u << (myidx & 31));
}

// ---------------- K4a: compaction + segment gather, 8-deep ILP ------------------
// grid (NSEG, B_) = 512 blocks, block 512 (4 row-slots x 128 cols).
__global__ void k4a_gather(const float* __restrict__ x,
                           const unsigned int* __restrict__ maskG,
                           int* __restrict__ cntU,
                           double* __restrict__ partial) {
  __shared__ int list[MAXU];        // 2.56 KB
  __shared__ int wtot[8], wbase[8];
  __shared__ int cntS;
  __shared__ double red[4][DIM];    // 4 KB
  const int seg = blockIdx.x, b = blockIdx.y, tid = threadIdx.x;
  const int w = tid >> 6, lane = tid & 63;
  unsigned wd[2];
  int c = 0;
#pragma unroll
  for (int k = 0; k < 2; ++k) {
    wd[k] = maskG[b * NMW + tid * 2 + k];
    c += __popc(wd[k]);
  }
  int incl = c;
#pragma unroll
  for (int o = 1; o < 64; o <<= 1) {
    int up = __shfl_up(incl, o, 64);
    if (lane >= o) incl += up;
  }
  if (lane == 63) wtot[w] = incl;
  __syncthreads();
  if (tid == 0) {
    int s = 0;
#pragma unroll
    for (int i = 0; i < 8; ++i) { wbase[i] = s; s += wtot[i]; }
    cntS = s;
  }
  __syncthreads();
  int p = wbase[w] + incl - c;
#pragma unroll
  for (int k = 0; k < 2; ++k) {
    unsigned bits = wd[k];
    while (bits) {
      int bit = __ffs(bits) - 1;
      list[p++] = (tid * 2 + k) * 32 + bit;
      bits &= bits - 1;
    }
  }
  __syncthreads();
  const int n = cntS;
  if (seg == 0 && tid == 0) cntU[b] = n;
  const int r0 = (seg * n) / NSEG, r1 = ((seg + 1) * n) / NSEG;
  const int slot = tid >> 7, col = tid & 127;  // 4 slots x 128 cols
  const float* xb = x + (size_t)b * NV * DIM;
  double a0 = 0, a1 = 0, a2 = 0, a3 = 0, a4 = 0, a5 = 0, a6 = 0, a7 = 0;
  int i = r0 + slot;
  for (; i + 28 < r1; i += 32) {   // 8 loads in flight per slot
    float v0 = xb[(size_t)list[i +  0] * DIM + col];
    float v1 = xb[(size_t)list[i +  4] * DIM + col];
    float v2 = xb[(size_t)list[i +  8] * DIM + col];
    float v3 = xb[(size_t)list[i + 12] * DIM + col];
    float v4 = xb[(size_t)list[i + 16] * DIM + col];
    float v5 = xb[(size_t)list[i + 20] * DIM + col];
    float v6 = xb[(size_t)list[i + 24] * DIM + col];
    float v7 = xb[(size_t)list[i + 28] * DIM + col];
    a0 += (double)v0; a1 += (double)v1; a2 += (double)v2; a3 += (double)v3;
    a4 += (double)v4; a5 += (double)v5; a6 += (double)v6; a7 += (double)v7;
  }
  for (; i < r1; i += 4) a0 += (double)xb[(size_t)list[i] * DIM + col];
  red[slot][col] = (((a0 + a1) + (a2 + a3)) + ((a4 + a5) + (a6 + a7)));
  __syncthreads();
  if (tid < DIM)
    partial[((size_t)b * NSEG + seg) * DIM + tid] =
        (red[0][tid] + red[1][tid]) + (red[2][tid] + red[3][tid]);
}

// ---------------- K4b: reduce partials + top_net MLP (4-way dd split) -----------
// grid B_, block 512.
__global__ void k4b_mlp(const double* __restrict__ partial,
                        const int* __restrict__ cntU,
                        const float* __restrict__ W1, const float* __restrict__ b1,
                        const float* __restrict__ gamma, const float* __restrict__ beta,
                        const float* __restrict__ rm, const float* __restrict__ rv,
                        const float* __restrict__ W2, const float* __restrict__ b2,
                        float* __restrict__ out) {
  __shared__ float embS[DIM];
  __shared__ float hpart[4][DIM];
  __shared__ float hS[DIM];
  const int b = blockIdx.x, t = threadIdx.x;
  if (t < DIM) {
    double s = 0;
#pragma unroll
    for (int seg = 0; seg < NSEG; ++seg)
      s += partial[((size_t)b * NSEG + seg) * DIM + t];
    embS[t] = (float)(s / (double)cntU[b]);
  }
  __syncthreads();
  {
    const int d = t & 127, q = t >> 7;   // 4 quarters x 32 dds
    float hp = 0.f;
    const int dd0 = q * 32;
#pragma unroll 8
    for (int dd = dd0; dd < dd0 + 32; ++dd) hp = fmaf(embS[dd], W1[dd * DIM + d], hp);
    hpart[q][d] = hp;
  }
  __syncthreads();
  if (t < DIM) {
    float h = ((hpart[0][t] + hpart[1][t]) + (hpart[2][t] + hpart[3][t])) + b1[t];
    h = (h - rm[t]) / sqrtf(rv[t] + 1e-5f) * gamma[t] + beta[t];
    h = h / (1.f + expf(-h));
    hS[t] = h;
  }
  __syncthreads();
  if (t < OUTD * 16) {
    const int o = t >> 4, g = t & 15;
    float p = 0.f;
#pragma unroll
    for (int dd = g * 8; dd < g * 8 + 8; ++dd) p = fmaf(hS[dd], W2[dd * OUTD + o], p);
#pragma unroll
    for (int off = 8; off >= 1; off >>= 1) p += __shfl_down(p, off, 16);
    if (g == 0) out[b * OUTD + o] = p + b2[o];
  }
}

extern "C" void kernel_launch(void* const* d_in, const int* in_sizes, int n_in,
                              void* d_out, int out_size, void* d_ws, size_t ws_size,
                              hipStream_t stream) {
  const float* pos  = (const float*)d_in[0];
  const float* x    = (const float*)d_in[1];
  const float* lig  = (const float*)d_in[2];
  const float* W1   = (const float*)d_in[3];
  const float* b1   = (const float*)d_in[4];
  const float* gam  = (const float*)d_in[5];
  const float* bet  = (const float*)d_in[6];
  const float* rm   = (const float*)d_in[7];
  const float* rv   = (const float*)d_in[8];
  const float* W2   = (const float*)d_in[9];
  const float* b2   = (const float*)d_in[10];
  float* out = (float*)d_out;

  // workspace carve-up
  char* ws = (char*)d_ws;
  const int NBL = B_ * LA;  // 2048
  unsigned int* cnt   = (unsigned int*)(ws);              // 8 KB
  unsigned int* maskG = (unsigned int*)(ws + 8192);       // 128 KB
  int* cntU           = (int*)(ws + 139264);              // 128 B
  float4* ligC        = (float4*)(ws + 139392);           // 32 KB (16-aligned)
  float* ligCl        = (float*)(ws + 172160);            // 8 KB
  double* partial     = (double*)(ws + 180352);           // 512 KB
  u64* cand           = (u64*)(ws + 704640);              // 8-aligned
  size_t fixed = 704640;
  size_t avail = ws_size > fixed ? ws_size - fixed : 0;
  int cap = (int)(avail / ((size_t)NBL * 8));
  if (cap > 1024) cap = 1024;
  if (cap < 16) cap = 16;

  k1_threshold<<<dim3(LA, B_), 64, 0, stream>>>(pos, lig, cnt, maskG, ligC, ligCl);
  k2_filter<<<dim3(NCH, B_), 256, 0, stream>>>(pos, ligC, ligCl, cnt, cand, cap);
  k3_select<<<NBL, 64, 0, stream>>>(cnt, cand, cap, maskG);
  k4a_gather<<<dim3(NSEG, B_), 512, 0, stream>>>(x, maskG, cntU, partial);
  k4b_mlp<<<B_, 512, 0, stream>>>(partial, cntU, W1, b1, gam, bet, rm, rv, W2, b2, out);
}

// Round 24
// 59.296 us; speedup vs baseline: 1.2094x; 1.2094x over previous
//
#include <hip/hip_runtime.h>
#include <math.h>

#define B_    32
#define NV    32768
#define LA    64
#define DIM   128
#define OUTD  7
#define TOPK  10
#define CHUNK 1024
#define NCH   (NV / CHUNK)   // 32
#define NMW   (NV / 32)      // 1024 mask words per batch
#define MAXU  (LA * TOPK)    // 640
#define NSEG  16             // gather segments per batch
#define LCAP  24             // LDS candidate slots per (block, ligand)

typedef unsigned long long u64;

// ---------------- K1: per-(b,l) sample threshold via lane-min tree --------------
// grid (LA, B_), block 64. T = 10th smallest of the 64 lane-minima over 16
// samples each (valid upper bound on true 10th-NN d2: >=10 lanes have min <= T
// => >=10 samples <= T => sample-10th <= T). Zeros cnt + maskG.
__global__ void k1_threshold(const float* __restrict__ pos,
                             const float* __restrict__ lig,
                             float* __restrict__ T, unsigned int* __restrict__ cnt,
                             unsigned int* __restrict__ maskG) {
  const int l = blockIdx.x, b = blockIdx.y;
  const int lane = threadIdx.x;
  const int bl = b * LA + l;
  if (lane == 0) cnt[bl] = 0u;
  if (lane >= 32 && lane < 48) maskG[b * NMW + l * 16 + (lane - 32)] = 0u;
  const float lx = lig[bl * 3 + 0];
  const float ly = lig[bl * 3 + 1];
  const float lz = lig[bl * 3 + 2];
  const float* pb = pos + (size_t)b * NV * 3;
  float d2a[16];
#pragma unroll
  for (int k = 0; k < 16; ++k) {            // 16 independent evals
    int v = lane + 64 * k;
    float dx = pb[v * 3 + 0] - lx;
    float dy = pb[v * 3 + 1] - ly;
    float dz = pb[v * 3 + 2] - lz;
    d2a[k] = fmaf(dx, dx, fmaf(dy, dy, dz * dz));
  }
  // lane min (15 ops, tree)
#pragma unroll
  for (int st = 8; st >= 1; st >>= 1)
#pragma unroll
    for (int k = 0; k < 16; ++k)
      if (k < st) d2a[k] = fminf(d2a[k], d2a[k + st]);
  float mymin = d2a[0];
  // 10 rounds of wave-min + consume over lane minima (ties consumed together:
  // only enlarges T -> still a valid upper bound)
  float T10 = 0.f;
  for (int r = 0; r < TOPK; ++r) {
    float v = mymin;
#pragma unroll
    for (int o = 1; o < 64; o <<= 1) v = fminf(v, __shfl_xor(v, o, 64));
    T10 = v;
    if (mymin == v) mymin = INFINITY;
  }
  if (lane == 0) T[bl] = T10;
}

// ---------------- K2: filter; emits u64 (d2|idx) keys, LDS-buffered -------------
// grid (NCH, B_) = 1024 blocks, block 512. Thread = (lg=tid>>4 in 0..31,
// vl=tid&15); ligands {lg, lg+32}, verts {vl+16k}. (R20-proven shape.)
__global__ void k2_filter(const float* __restrict__ pos,
                          const float* __restrict__ lig,
                          const float* __restrict__ T,
                          unsigned int* __restrict__ cnt,
                          u64* __restrict__ cand, int cap) {
  __shared__ float4 vp[CHUNK];          // 16 KB
  __shared__ u64 lcand[LA][LCAP];       // 12 KB
  __shared__ unsigned lcnt[LA];         // 256 B
  __shared__ unsigned gbaseS[LA];       // 256 B
  const int c = blockIdx.x, b = blockIdx.y;
  const int tid = threadIdx.x;
  const int base = c * CHUNK;
  const float* pb = pos + ((size_t)b * NV + base) * 3;
  for (int j = tid; j < CHUNK * 3; j += 512) {
    int v = j / 3, comp = j - 3 * v;
    float val = pb[j];
    if (comp == 0) vp[v].x = val;
    else if (comp == 1) vp[v].y = val;
    else vp[v].z = val;
  }
  if (tid < LA) lcnt[tid] = 0u;
  __syncthreads();
  for (int v = tid; v < CHUNK; v += 512) {
    float px = vp[v].x, py = vp[v].y, pz = vp[v].z;
    vp[v].w = fmaf(px, px, fmaf(py, py, pz * pz));
  }
  __syncthreads();
  const int lg = tid >> 4, vl = tid & 15;
  float Ax[2], Ay[2], Az[2], TH[2], Cl[2];
#pragma unroll
  for (int j = 0; j < 2; ++j) {
    int l = lg + 32 * j;
    float lx = lig[(b * LA + l) * 3 + 0];
    float ly = lig[(b * LA + l) * 3 + 1];
    float lz = lig[(b * LA + l) * 3 + 2];
    Ax[j] = -2.f * lx; Ay[j] = -2.f * ly; Az[j] = -2.f * lz;
    Cl[j] = lx * lx + ly * ly + lz * lz;
    TH[j] = T[b * LA + l] + 0.01f - Cl[j];
  }
  for (int k = 0; k < CHUNK / 16; ++k) {
    int v = vl + 16 * k;
    float4 p = vp[v];
#pragma unroll
    for (int j = 0; j < 2; ++j) {
      float t = fmaf(p.x, Ax[j], fmaf(p.y, Ay[j], fmaf(p.z, Az[j], p.w)));
      if (t <= TH[j]) {
        int l = lg + 32 * j;
        float d2 = fmaxf(t + Cl[j], 0.f);   // clamp keeps bit-order monotone
        u64 key = ((u64)__float_as_uint(d2) << 32) | (unsigned)(base + v);
        unsigned p2 = atomicAdd(&lcnt[l], 1u);
        if (p2 < (unsigned)LCAP) lcand[l][p2] = key;
        else {  // rare overflow: direct global append (set still complete)
          unsigned pidx = atomicAdd(&cnt[b * LA + l], 1u);
          if (pidx < (unsigned)cap) cand[(size_t)(b * LA + l) * cap + pidx] = key;
        }
      }
    }
  }
  __syncthreads();
  if (tid < LA) {
    int mcount = (int)min(lcnt[tid], (unsigned)LCAP);
    gbaseS[tid] = (mcount > 0) ? atomicAdd(&cnt[b * LA + tid], (unsigned)mcount) : 0u;
  }
  __syncthreads();
  for (int idx = tid; idx < LA * LCAP; idx += 512) {
    const int ll = idx / LCAP, i = idx - ll * LCAP;
    if (i < (int)min(lcnt[ll], (unsigned)LCAP)) {
      unsigned g = gbaseS[ll] + (unsigned)i;
      if (g < (unsigned)cap) cand[(size_t)(b * LA + ll) * cap + g] = lcand[ll][i];
    }
  }
}

// ---------------- K3: exact top-10 merge over precomputed keys, 1 wave/task -----
// grid 2048, block 64.
__global__ void k3_select(const unsigned int* __restrict__ cnt,
                          const u64* __restrict__ cand, int cap,
                          unsigned int* __restrict__ maskG) {
  const int bl = blockIdx.x;
  const int b = bl / LA;
  const int lane = threadIdx.x;
  int n = (int)min(cnt[bl], (unsigned)cap);
  u64 s[TOPK];
#pragma unroll
  for (int i = 0; i < TOPK; ++i) s[i] = 0xFFFFFFFFFFFFFFFFull;
  for (int i = lane; i < n; i += 64) {
    u64 key = cand[(size_t)bl * cap + i];
    if (key < s[TOPK - 1]) {
      s[TOPK - 1] = key;
#pragma unroll
      for (int i2 = TOPK - 1; i2 >= 1; --i2)
        if (s[i2] < s[i2 - 1]) { u64 t = s[i2]; s[i2] = s[i2 - 1]; s[i2 - 1] = t; }
    }
  }
  int prev = 0, myidx = 0;
  for (int r = 0; r < TOPK; ++r) {
    u64 v = s[0];
#pragma unroll
    for (int o = 1; o < 64; o <<= 1) {
      u64 other = __shfl_xor(v, o, 64);
      v = (other < v) ? other : v;
    }
    if (s[0] == v) {  // keys unique: exact consume
#pragma unroll
      for (int i = 0; i < TOPK - 1; ++i) s[i] = s[i + 1];
      s[TOPK - 1] = 0xFFFFFFFFFFFFFFFFull;
    }
    int idx = (int)(unsigned)(v & 0xFFFFFFFFu);
    if ((v >> 32) == 0xFFFFFFFFull) idx = prev;  // pad guard (n>=10 always)
    prev = idx;
    if (lane == r) myidx = idx;
  }
  if (lane < TOPK)
    atomicOr(&maskG[b * NMW + (myidx >> 5)], 1u << (myidx & 31));
}

// ---------------- K4a: compaction + segment gather, 8-deep ILP ------------------
// grid (NSEG, B_) = 512 blocks, block 512 (4 row-slots x 128 cols).
__global__ void k4a_gather(const float* __restrict__ x,
                           const unsigned int* __restrict__ maskG,
                           int* __restrict__ cntU,
                           double* __restrict__ partial) {
  __shared__ int list[MAXU];        // 2.56 KB
  __shared__ int wtot[8], wbase[8];
  __shared__ int cntS;
  __shared__ double red[4][DIM];    // 4 KB
  const int seg = blockIdx.x, b = blockIdx.y, tid = threadIdx.x;
  const int w = tid >> 6, lane = tid & 63;
  unsigned wd[2];
  int c = 0;
#pragma unroll
  for (int k = 0; k < 2; ++k) {
    wd[k] = maskG[b * NMW + tid * 2 + k];
    c += __popc(wd[k]);
  }
  int incl = c;
#pragma unroll
  for (int o = 1; o < 64; o <<= 1) {
    int up = __shfl_up(incl, o, 64);
    if (lane >= o) incl += up;
  }
  if (lane == 63) wtot[w] = incl;
  __syncthreads();
  if (tid == 0) {
    int s = 0;
#pragma unroll
    for (int i = 0; i < 8; ++i) { wbase[i] = s; s += wtot[i]; }
    cntS = s;
  }
  __syncthreads();
  int p = wbase[w] + incl - c;
#pragma unroll
  for (int k = 0; k < 2; ++k) {
    unsigned bits = wd[k];
    while (bits) {
      int bit = __ffs(bits) - 1;
      list[p++] = (tid * 2 + k) * 32 + bit;
      bits &= bits - 1;
    }
  }
  __syncthreads();
  const int n = cntS;
  if (seg == 0 && tid == 0) cntU[b] = n;
  const int r0 = (seg * n) / NSEG, r1 = ((seg + 1) * n) / NSEG;
  const int slot = tid >> 7, col = tid & 127;  // 4 slots x 128 cols
  const float* xb = x + (size_t)b * NV * DIM;
  double a0 = 0, a1 = 0, a2 = 0, a3 = 0, a4 = 0, a5 = 0, a6 = 0, a7 = 0;
  int i = r0 + slot;
  for (; i + 28 < r1; i += 32) {   // 8 loads in flight per slot
    float v0 = xb[(size_t)list[i +  0] * DIM + col];
    float v1 = xb[(size_t)list[i +  4] * DIM + col];
    float v2 = xb[(size_t)list[i +  8] * DIM + col];
    float v3 = xb[(size_t)list[i + 12] * DIM + col];
    float v4 = xb[(size_t)list[i + 16] * DIM + col];
    float v5 = xb[(size_t)list[i + 20] * DIM + col];
    float v6 = xb[(size_t)list[i + 24] * DIM + col];
    float v7 = xb[(size_t)list[i + 28] * DIM + col];
    a0 += (double)v0; a1 += (double)v1; a2 += (double)v2; a3 += (double)v3;
    a4 += (double)v4; a5 += (double)v5; a6 += (double)v6; a7 += (double)v7;
  }
  for (; i < r1; i += 4) a0 += (double)xb[(size_t)list[i] * DIM + col];
  red[slot][col] = (((a0 + a1) + (a2 + a3)) + ((a4 + a5) + (a6 + a7)));
  __syncthreads();
  if (tid < DIM)
    partial[((size_t)b * NSEG + seg) * DIM + tid] =
        (red[0][tid] + red[1][tid]) + (red[2][tid] + red[3][tid]);
}

// ---------------- K4b: reduce partials + top_net MLP (4-way dd split) -----------
// grid B_, block 512.
__global__ void k4b_mlp(const double* __restrict__ partial,
                        const int* __restrict__ cntU,
                        const float* __restrict__ W1, const float* __restrict__ b1,
                        const float* __restrict__ gamma, const float* __restrict__ beta,
                        const float* __restrict__ rm, const float* __restrict__ rv,
                        const float* __restrict__ W2, const float* __restrict__ b2,
                        float* __restrict__ out) {
  __shared__ float embS[DIM];
  __shared__ float hpart[4][DIM];
  __shared__ float hS[DIM];
  const int b = blockIdx.x, t = threadIdx.x;
  if (t < DIM) {
    double s = 0;
#pragma unroll
    for (int seg = 0; seg < NSEG; ++seg)
      s += partial[((size_t)b * NSEG + seg) * DIM + t];
    embS[t] = (float)(s / (double)cntU[b]);
  }
  __syncthreads();
  {
    const int d = t & 127, q = t >> 7;   // 4 quarters x 32 dds
    float hp = 0.f;
    const int dd0 = q * 32;
#pragma unroll 8
    for (int dd = dd0; dd < dd0 + 32; ++dd) hp = fmaf(embS[dd], W1[dd * DIM + d], hp);
    hpart[q][d] = hp;
  }
  __syncthreads();
  if (t < DIM) {
    float h = ((hpart[0][t] + hpart[1][t]) + (hpart[2][t] + hpart[3][t])) + b1[t];
    h = (h - rm[t]) / sqrtf(rv[t] + 1e-5f) * gamma[t] + beta[t];
    h = h / (1.f + expf(-h));
    hS[t] = h;
  }
  __syncthreads();
  if (t < OUTD * 16) {
    const int o = t >> 4, g = t & 15;
    float p = 0.f;
#pragma unroll
    for (int dd = g * 8; dd < g * 8 + 8; ++dd) p = fmaf(hS[dd], W2[dd * OUTD + o], p);
#pragma unroll
    for (int off = 8; off >= 1; off >>= 1) p += __shfl_down(p, off, 16);
    if (g == 0) out[b * OUTD + o] = p + b2[o];
  }
}

extern "C" void kernel_launch(void* const* d_in, const int* in_sizes, int n_in,
                              void* d_out, int out_size, void* d_ws, size_t ws_size,
                              hipStream_t stream) {
  const float* pos  = (const float*)d_in[0];
  const float* x    = (const float*)d_in[1];
  const float* lig  = (const float*)d_in[2];
  const float* W1   = (const float*)d_in[3];
  const float* b1   = (const float*)d_in[4];
  const float* gam  = (const float*)d_in[5];
  const float* bet  = (const float*)d_in[6];
  const float* rm   = (const float*)d_in[7];
  const float* rv   = (const float*)d_in[8];
  const float* W2   = (const float*)d_in[9];
  const float* b2   = (const float*)d_in[10];
  float* out = (float*)d_out;

  // workspace carve-up
  char* ws = (char*)d_ws;
  const int NBL = B_ * LA;  // 2048
  float* T            = (float*)(ws);                     // 8 KB
  unsigned int* cnt   = (unsigned int*)(ws + 8192);       // 8 KB
  unsigned int* maskG = (unsigned int*)(ws + 16384);      // 128 KB
  int* cntU           = (int*)(ws + 147456);              // 128 B
  double* partial     = (double*)(ws + 147584);           // 512 KB
  u64* cand           = (u64*)(ws + 671872);              // 8-aligned
  size_t fixed = 671872;
  size_t avail = ws_size > fixed ? ws_size - fixed : 0;
  int cap = (int)(avail / ((size_t)NBL * 8));
  if (cap > 1024) cap = 1024;
  if (cap < 16) cap = 16;

  k1_threshold<<<dim3(LA, B_), 64, 0, stream>>>(pos, lig, T, cnt, maskG);
  k2_filter<<<dim3(NCH, B_), 512, 0, stream>>>(pos, lig, T, cnt, cand, cap);
  k3_select<<<NBL, 64, 0, stream>>>(cnt, cand, cap, maskG);
  k4a_gather<<<dim3(NSEG, B_), 512, 0, stream>>>(x, maskG, cntU, partial);
  k4b_mlp<<<B_, 512, 0, stream>>>(partial, cntU, W1, b1, gam, bet, rm, rv, W2, b2, out);
}